// Round 2
// baseline (1061.084 us; speedup 1.0000x reference)
//
#include <hip/hip_runtime.h>
#include <hip/hip_bf16.h>

// ---- problem constants ----
#define BSZ  32
#define CTX  8192
#define NP_  512
#define PSZ  16
#define DM_  1024
#define DS_  16
#define DI_  2048
#define DTR_ 64
#define NTOK (BSZ*NP_)   // 16384

typedef __hip_bfloat16 bf16;
typedef short bf16x8 __attribute__((ext_vector_type(8)));
typedef float f32x4  __attribute__((ext_vector_type(4)));

typedef __attribute__((address_space(3))) void lds_t;
typedef __attribute__((address_space(1))) void gbl_t;

__device__ inline float bf2f(bf16 v){ return __bfloat162float(v); }
__device__ inline bf16  f2bf(float v){ return __float2bfloat16(v); }
__device__ inline float fast_sigmoid(float x){ return 1.0f/(1.0f+__expf(-x)); }
__device__ inline float softplusf(float x){ return x>15.0f ? x : log1pf(__expf(x)); }
__device__ inline void stout(float* p, float v){ *p = v; }
__device__ inline void stout(bf16* p, float v){ *p = f2bf(v); }

__device__ inline void gload_lds16(const void* g, void* l){
  __builtin_amdgcn_global_load_lds((const gbl_t*)g, (lds_t*)l, 16, 0, 0);
}

// ---- sincos positional embedding table [NP, DM] ----
__global__ __launch_bounds__(256) void k_posemb(float* __restrict__ pe){
  int idx = blockIdx.x*256 + threadIdx.x;          // 512*1024
  int n = idx >> 10, c = idx & 1023;
  int j2 = c & 511;
  float omega = exp2f(-13.2877123795495f * ((float)j2 * (1.0f/511.0f)));
  float ang = (float)n * omega;
  pe[idx] = (c < 512) ? sinf(ang) : cosf(ang);
}

// ---- weight prep: transpose + bf16 convert ----
// T[n][k] = W_in[k][col0+n], n<2048, k<1024  (one half of in_proj, transposed)
__global__ __launch_bounds__(256) void k_prep_winT_half(const float* __restrict__ W, bf16* __restrict__ T, int col0){
  int idx = blockIdx.x*256 + threadIdx.x;          // 2048*1024
  int n = idx >> 10, k = idx & 1023;
  T[idx] = f2bf(W[(size_t)k*4096 + col0 + n]);
}
__global__ __launch_bounds__(256) void k_prep_wxT(const float* __restrict__ W, bf16* __restrict__ T){
  int idx = blockIdx.x*256 + threadIdx.x;          // [128,2048] out (pad rows 96..127 = 0)
  int j = idx >> 11, k = idx & 2047;
  T[idx] = f2bf(j < 96 ? W[(size_t)k*96 + j] : 0.0f);
}
__global__ __launch_bounds__(256) void k_prep_wdtT(const float* __restrict__ W, bf16* __restrict__ T){
  int idx = blockIdx.x*256 + threadIdx.x;          // [2048,64] out
  int d = idx >> 6, k = idx & 63;
  T[idx] = f2bf(W[(size_t)k*2048 + d]);
}
__global__ __launch_bounds__(256) void k_cvt_dt(const float* __restrict__ xd, bf16* __restrict__ dt){
  int idx = blockIdx.x*256 + threadIdx.x;          // [16384,64] out from xd[:, :64]
  int t = idx >> 6, j = idx & 63;
  dt[idx] = f2bf(xd[(size_t)t*128 + j]);
}

// ---- patch embedding: LN(16) -> Linear(16,1024) -> LN(1024) -> +posemb -> bf16 ----
__global__ __launch_bounds__(256) void k_patch(
    const float* __restrict__ x, const float* __restrict__ g1, const float* __restrict__ b1,
    const float* __restrict__ Wp, const float* __restrict__ bp,
    const float* __restrict__ g2, const float* __restrict__ b2,
    const float* __restrict__ pe, bf16* __restrict__ h)
{
  __shared__ float sp[16];
  __shared__ float red[8];
  int tok = blockIdx.x, tid = threadIdx.x;
  int b = tok >> 9, n = tok & 511;
  if (tid < 16) sp[tid] = x[(size_t)b*CTX + n*16 + tid];
  __syncthreads();
  float m = 0.f;
  #pragma unroll
  for (int i=0;i<16;i++) m += sp[i];
  m *= (1.0f/16.0f);
  float v = 0.f;
  #pragma unroll
  for (int i=0;i<16;i++){ float d = sp[i]-m; v += d*d; }
  v *= (1.0f/16.0f);
  float rs = rsqrtf(v + 1e-5f);
  float pn[16];
  #pragma unroll
  for (int i=0;i<16;i++) pn[i] = (sp[i]-m)*rs*g1[i] + b1[i];
  float acc[4];
  #pragma unroll
  for (int q=0;q<4;q++){
    int j = tid + q*256;
    float a = bp[j];
    #pragma unroll
    for (int i=0;i<16;i++) a += pn[i]*Wp[i*1024 + j];
    acc[q] = a;
  }
  float s1 = acc[0]+acc[1]+acc[2]+acc[3];
  float s2 = acc[0]*acc[0]+acc[1]*acc[1]+acc[2]*acc[2]+acc[3]*acc[3];
  #pragma unroll
  for (int o=32;o;o>>=1){ s1 += __shfl_down(s1,o,64); s2 += __shfl_down(s2,o,64); }
  int w = tid>>6, l = tid&63;
  if (l==0){ red[w]=s1; red[4+w]=s2; }
  __syncthreads();
  float mu  = (red[0]+red[1]+red[2]+red[3])*(1.0f/1024.0f);
  float var = (red[4]+red[5]+red[6]+red[7])*(1.0f/1024.0f) - mu*mu;
  float rs2 = rsqrtf(var + 1e-5f);
  #pragma unroll
  for (int q=0;q<4;q++){
    int j = tid + q*256;
    float val = (acc[q]-mu)*rs2*g2[j] + b2[j] + pe[n*1024 + j];
    h[(size_t)tok*1024 + j] = f2bf(val);
  }
}

// ---- bf16 MFMA GEMM: C[M,N] = A[M,K] @ B[K,N], B given transposed (BT[N,K] row-major) ----
// 128x128 tile, BK=32, 4 waves (2x2), per-wave 64x64 = 4x4 16x16x32 MFMA frags.
// EPI: 0 = plain store, 1 = softplus(acc + bias[col]).
template<int EPI, typename OT>
__global__ __launch_bounds__(256) void k_gemm_bt(
    const bf16* __restrict__ A, const bf16* __restrict__ BT, OT* __restrict__ C,
    int M, int N, int K, const float* __restrict__ bias)
{
  __shared__ __align__(16) bf16 As[128*32];
  __shared__ __align__(16) bf16 Bs[128*32];
  int tid = threadIdx.x;
  int mblk = M >> 7;
  int bm = blockIdx.x % mblk, bn = blockIdx.x / mblk;
  int m0 = bm << 7, n0 = bn << 7;
  int w = tid >> 6, l = tid & 63, lr = l & 15, lg = l >> 4;
  int wm = w >> 1, wn = w & 1;
  f32x4 acc[4][4] = {};
  // staging: thread covers 8 contiguous bf16; wave w covers 16 rows (q=0: 0..63, q=1: 64..127)
  int r0 = tid >> 2, c0 = (tid & 3) << 3;
  const bf16* Asrc = A  + (size_t)(m0 + r0) * K + c0;
  const bf16* Bsrc = BT + (size_t)(n0 + r0) * K + c0;
  bf16* AsW = As + w*512;   // wave-uniform LDS base (lane-linear, 64 lanes x 16B)
  bf16* BsW = Bs + w*512;
  for (int kt = 0; kt < K; kt += 32){
    __syncthreads();
    gload_lds16(Asrc + kt,                   AsW);
    gload_lds16(Asrc + (size_t)64*K + kt,    AsW + 2048);
    gload_lds16(Bsrc + kt,                   BsW);
    gload_lds16(Bsrc + (size_t)64*K + kt,    BsW + 2048);
    __syncthreads();
    bf16x8 af[4], bfr[4];
    #pragma unroll
    for (int i=0;i<4;i++) af[i]  = *(const bf16x8*)(As + (wm*64 + i*16 + lr)*32 + lg*8);
    #pragma unroll
    for (int j=0;j<4;j++) bfr[j] = *(const bf16x8*)(Bs + (wn*64 + j*16 + lr)*32 + lg*8);
    #pragma unroll
    for (int i=0;i<4;i++)
      #pragma unroll
      for (int j=0;j<4;j++)
        acc[i][j] = __builtin_amdgcn_mfma_f32_16x16x32_bf16(af[i], bfr[j], acc[i][j], 0,0,0);
  }
  #pragma unroll
  for (int i=0;i<4;i++)
    #pragma unroll
    for (int j=0;j<4;j++)
      #pragma unroll
      for (int r=0;r<4;r++){
        int row = wm*64 + i*16 + lg*4 + r;   // C/D: col=lane&15, row=(lane>>4)*4+reg
        int col = wn*64 + j*16 + lr;
        float v = acc[i][j][r];
        if (EPI == 1) v = softplusf(v + bias[n0 + col]);
        stout(&C[(size_t)(m0+row)*N + n0 + col], v);
      }
}

// ---- causal depthwise conv (DC=4) + SiLU, bf16 in/out ; u stride 2048 ----
__global__ __launch_bounds__(256) void k_conv(
    const bf16* __restrict__ u, const float* __restrict__ cw, const float* __restrict__ cb,
    bf16* __restrict__ uc)
{
  const int total = NTOK*DI_;
  for (int idx = blockIdx.x*256 + threadIdx.x; idx < total; idx += gridDim.x*256){
    int d = idx & 2047;
    int tok = idx >> 11;
    int n = tok & 511;
    float a = cb[d];
    #pragma unroll
    for (int k=0;k<4;k++){
      int nn = n + k - 3;
      if (nn >= 0) a += bf2f(u[(size_t)(tok + k - 3)*2048 + d]) * cw[d*4 + k];
    }
    uc[idx] = f2bf(a * fast_sigmoid(a));
  }
}

// ---- selective scan, fused gate + token-sum: ysum[b,d] = sum_t (y+u*D)*silu(z) ----
__global__ __launch_bounds__(256) void k_scan(
    const bf16* __restrict__ delta, const bf16* __restrict__ uc, const bf16* __restrict__ z,
    const float* __restrict__ xd, const float* __restrict__ A_log,
    const float* __restrict__ Dp, float* __restrict__ ysum)
{
  int tid = threadIdx.x;
  int b = blockIdx.x >> 3;
  int d = ((blockIdx.x & 7) << 8) + tid;
  float An[16];
  const float4* a4 = (const float4*)(A_log + (size_t)d*16);
  #pragma unroll
  for (int q=0;q<4;q++){
    float4 t = a4[q];
    An[q*4+0] = -__expf(t.x); An[q*4+1] = -__expf(t.y);
    An[q*4+2] = -__expf(t.z); An[q*4+3] = -__expf(t.w);
  }
  float Dd = Dp[d];
  float h[16];
  #pragma unroll
  for (int n=0;n<16;n++) h[n] = 0.0f;
  float acc = 0.0f;
  size_t tok0 = (size_t)b * 512;
  for (int t=0; t<512; ++t){
    size_t tok = tok0 + t;
    float dt = bf2f(delta[tok*2048 + d]);
    float ut = bf2f(uc[tok*2048 + d]);
    float zt = bf2f(z[tok*2048 + d]);
    const float4* x4 = (const float4*)(xd + tok*128);   // cols: 0..63 dt, 64..79 B, 80..95 C
    float du = dt*ut;
    float y = 0.0f;
    #pragma unroll
    for (int q=0;q<4;q++){
      float4 Bq = x4[16+q];
      float4 Cq = x4[20+q];
      float e;
      e = __expf(dt*An[q*4+0]); h[q*4+0] = h[q*4+0]*e + du*Bq.x; y += h[q*4+0]*Cq.x;
      e = __expf(dt*An[q*4+1]); h[q*4+1] = h[q*4+1]*e + du*Bq.y; y += h[q*4+1]*Cq.y;
      e = __expf(dt*An[q*4+2]); h[q*4+2] = h[q*4+2]*e + du*Bq.z; y += h[q*4+2]*Cq.z;
      e = __expf(dt*An[q*4+3]); h[q*4+3] = h[q*4+3]*e + du*Bq.w; y += h[q*4+3]*Cq.w;
    }
    acc += (y + ut*Dd) * (zt * fast_sigmoid(zt));
  }
  ysum[(size_t)b*2048 + d] = acc;
}

// ---- pooled = (ysum/NP) @ W_out : [32,2048] @ [2048,1024] ----
__global__ __launch_bounds__(256) void k_poolgemm(
    const float* __restrict__ ysum, const float* __restrict__ Wo, float* __restrict__ pooled)
{
  __shared__ float ys[32*128];
  int tid = threadIdx.x;
  int nb = blockIdx.x;                  // 16 blocks x 64 cols
  int jj = tid & 63, b0 = tid >> 6;
  int j = nb*64 + jj;
  float acc[8];
  #pragma unroll
  for (int p=0;p<8;p++) acc[p] = 0.f;
  for (int kc=0; kc<2048; kc+=128){
    __syncthreads();
    #pragma unroll
    for (int i=0;i<16;i++){
      int e = tid + i*256;
      int bb = e >> 7, kk = e & 127;
      ys[bb*128 + kk] = ysum[(size_t)bb*2048 + kc + kk];
    }
    __syncthreads();
    for (int kk=0;kk<128;kk++){
      float wv = Wo[(size_t)(kc+kk)*1024 + j];
      #pragma unroll
      for (int p=0;p<8;p++) acc[p] += ys[(b0 + p*4)*128 + kk] * wv;
    }
  }
  #pragma unroll
  for (int p=0;p<8;p++) pooled[(size_t)(b0 + p*4)*1024 + j] = acc[p] * (1.0f/512.0f);
}

// ---- head: LN(1024) -> dot Wh + bh ----
__global__ __launch_bounds__(256) void k_head(
    const float* __restrict__ pooled, const float* __restrict__ g, const float* __restrict__ bb,
    const float* __restrict__ Wh, const float* __restrict__ bh, float* __restrict__ out)
{
  __shared__ float red[8];
  int b = blockIdx.x, tid = threadIdx.x;
  float v[4];
  #pragma unroll
  for (int q=0;q<4;q++) v[q] = pooled[(size_t)b*1024 + tid + q*256];
  float s1 = v[0]+v[1]+v[2]+v[3];
  float s2 = v[0]*v[0]+v[1]*v[1]+v[2]*v[2]+v[3]*v[3];
  #pragma unroll
  for (int o=32;o;o>>=1){ s1 += __shfl_down(s1,o,64); s2 += __shfl_down(s2,o,64); }
  int w = tid>>6, l = tid&63;
  if (l==0){ red[w]=s1; red[4+w]=s2; }
  __syncthreads();
  float mu  = (red[0]+red[1]+red[2]+red[3])*(1.0f/1024.0f);
  float var = (red[4]+red[5]+red[6]+red[7])*(1.0f/1024.0f) - mu*mu;
  float rs = rsqrtf(var + 1e-5f);
  float p = 0.f;
  #pragma unroll
  for (int q=0;q<4;q++){
    int jv = tid + q*256;
    p += ((v[q]-mu)*rs*g[jv] + bb[jv]) * Wh[jv];
  }
  #pragma unroll
  for (int o=32;o;o>>=1) p += __shfl_down(p,o,64);
  __syncthreads();
  if (l==0) red[w] = p;
  __syncthreads();
  if (tid==0) out[b] = red[0]+red[1]+red[2]+red[3] + bh[0];
}

extern "C" void kernel_launch(void* const* d_in, const int* in_sizes, int n_in,
                              void* d_out, int out_size, void* d_ws, size_t ws_size,
                              hipStream_t stream)
{
  const float* x     = (const float*)d_in[0];
  const float* ln1_g = (const float*)d_in[1];
  const float* ln1_b = (const float*)d_in[2];
  const float* Wp    = (const float*)d_in[3];
  const float* bp    = (const float*)d_in[4];
  const float* ln2_g = (const float*)d_in[5];
  const float* ln2_b = (const float*)d_in[6];
  const float* W_in  = (const float*)d_in[7];
  const float* conv_w= (const float*)d_in[8];
  const float* conv_b= (const float*)d_in[9];
  const float* W_x   = (const float*)d_in[10];
  const float* W_dt  = (const float*)d_in[11];
  const float* b_dt  = (const float*)d_in[12];
  const float* A_log = (const float*)d_in[13];
  const float* Dv    = (const float*)d_in[14];
  const float* W_out = (const float*)d_in[15];
  const float* ln3_g = (const float*)d_in[16];
  const float* ln3_b = (const float*)d_in[17];
  const float* Wh    = (const float*)d_in[18];
  const float* bh    = (const float*)d_in[19];

  // ---- workspace layout with liveness-based aliasing; peak = 230 MiB ----
  char* ws = (char*)d_ws;
  size_t o = 0;
  bf16*  u_delta = (bf16*)(ws + o); o += (size_t)NTOK*DI_*2;   // 64 MiB: u, later delta
  bf16*  zbuf    = (bf16*)(ws + o); o += (size_t)NTOK*DI_*2;   // 64 MiB: z (persistent)
  bf16*  ucbuf   = (bf16*)(ws + o); o += (size_t)NTOK*DI_*2;   // 64 MiB: uc (persistent)
  char*  poolA   = (ws + o);        o += (size_t)NTOK*DM_*2;   // 32 MiB: h, later xd/dt/...
  bf16*  winTh   = (bf16*)(ws + o); o += (size_t)DI_*DM_*2;    //  4 MiB: one in_proj half ^T
  float* pe      = (float*)(ws + o); o += (size_t)NP_*DM_*4;   //  2 MiB
  // poolA phase-1: h [16384,1024] bf16
  bf16*  hbuf    = (bf16*)poolA;
  // poolA phase-2 (after in_proj GEMMs): xd, dt, wxT, wdtT, ysum, pooled
  float* xdbuf   = (float*)(poolA + 0);          // 8.0 MiB  [16384,128] f32
  bf16*  dtbuf   = (bf16*) (poolA + 8388608);    // 2.0 MiB  [16384,64]
  bf16*  wxT     = (bf16*) (poolA + 10485760);   // 0.5 MiB  [128,2048]
  bf16*  wdtT    = (bf16*) (poolA + 11010048);   // 0.25 MiB [2048,64]
  float* ysumbuf = (float*)(poolA + 11272192);   // 0.25 MiB [32,2048]
  float* pooledb = (float*)(poolA + 11534336);   // 0.13 MiB [32,1024]

  k_posemb        <<<2048, 256, 0, stream>>>(pe);
  k_patch         <<<16384,256, 0, stream>>>(x, ln1_g, ln1_b, Wp, bp, ln2_g, ln2_b, pe, hbuf);
  // in_proj, u half then z half (winTh reused)
  k_prep_winT_half<<<8192, 256, 0, stream>>>(W_in, winTh, 0);
  k_gemm_bt<0,bf16><<<2048,256, 0, stream>>>(hbuf, winTh, u_delta, NTOK, 2048, 1024, nullptr);
  k_prep_winT_half<<<8192, 256, 0, stream>>>(W_in, winTh, 2048);
  k_gemm_bt<0,bf16><<<2048,256, 0, stream>>>(hbuf, winTh, zbuf,    NTOK, 2048, 1024, nullptr);
  // conv(u) -> uc   (hbuf dead from here; poolA reused)
  k_conv          <<<8192, 256, 0, stream>>>(u_delta, conv_w, conv_b, ucbuf);
  // x_proj: xd = uc @ W_x  (N padded 96->128)
  k_prep_wxT      <<<1024, 256, 0, stream>>>(W_x, wxT);
  k_gemm_bt<0,float><<<128,256, 0, stream>>>(ucbuf, wxT, xdbuf, NTOK, 128, 2048, nullptr);
  // delta = softplus(dt @ W_dt + b_dt)  (overwrites u, dead after conv)
  k_cvt_dt        <<<4096, 256, 0, stream>>>(xdbuf, dtbuf);
  k_prep_wdtT     <<<512,  256, 0, stream>>>(W_dt, wdtT);
  k_gemm_bt<1,bf16><<<2048,256, 0, stream>>>(dtbuf, wdtT, u_delta, NTOK, 2048, 64, b_dt);
  // fused scan + D-skip + gate + token-sum
  k_scan          <<<256,  256, 0, stream>>>(u_delta, ucbuf, zbuf, xdbuf, A_log, Dv, ysumbuf);
  // pooled = (ysum/512) @ W_out ; head
  k_poolgemm      <<<16,   256, 0, stream>>>(ysumbuf, W_out, pooledb);
  k_head          <<<32,   256, 0, stream>>>(pooledb, ln3_g, ln3_b, Wh, bh, (float*)d_out);
  (void)in_sizes; (void)n_in; (void)out_size; (void)ws_size;
}

// Round 3
// 944.782 us; speedup vs baseline: 1.1231x; 1.1231x over previous
//
#include <hip/hip_runtime.h>
#include <hip/hip_bf16.h>

// ---- problem constants ----
#define BSZ  32
#define CTX  8192
#define NP_  512
#define PSZ  16
#define DM_  1024
#define DS_  16
#define DI_  2048
#define DTR_ 64
#define NTOK (BSZ*NP_)   // 16384

typedef __hip_bfloat16 bf16;
typedef short bf16x8 __attribute__((ext_vector_type(8)));
typedef float f32x4  __attribute__((ext_vector_type(4)));

typedef __attribute__((address_space(3))) void lds_t;
typedef __attribute__((address_space(1))) void gbl_t;

__device__ inline float bf2f(bf16 v){ return __bfloat162float(v); }
__device__ inline bf16  f2bf(float v){ return __float2bfloat16(v); }
__device__ inline float fast_sigmoid(float x){ return 1.0f/(1.0f+__expf(-x)); }
__device__ inline float softplusf(float x){ return x>15.0f ? x : log1pf(__expf(x)); }
__device__ inline void stout(float* p, float v){ *p = v; }
__device__ inline void stout(bf16* p, float v){ *p = f2bf(v); }

__device__ inline void gload_lds16(const void* g, void* l){
  __builtin_amdgcn_global_load_lds((const gbl_t*)g, (lds_t*)l, 16, 0, 0);
}

// ---- sincos positional embedding table [NP, DM] ----
__global__ __launch_bounds__(256) void k_posemb(float* __restrict__ pe){
  int idx = blockIdx.x*256 + threadIdx.x;          // 512*1024
  int n = idx >> 10, c = idx & 1023;
  int j2 = c & 511;
  float omega = exp2f(-13.2877123795495f * ((float)j2 * (1.0f/511.0f)));
  float ang = (float)n * omega;
  pe[idx] = (c < 512) ? sinf(ang) : cosf(ang);
}

// ---- coalesced transpose + f32->bf16: T[n][k] = W[k][col0+n] (n<nvalid else 0) ----
// T is [Nout, K] row-major, grid = (K/64, Nout/64), 64x64 LDS tile.
__global__ __launch_bounds__(256) void k_transpose_cvt(
    const float* __restrict__ W, bf16* __restrict__ T,
    int ldw, int col0, int nvalid, int K)
{
  __shared__ float tile[64][65];
  int tid = threadIdx.x;
  int kb = blockIdx.x << 6, nb = blockIdx.y << 6;
  int c = tid & 63, r4 = tid >> 6;
  #pragma unroll
  for (int i=0;i<16;i++){
    int r = r4 + i*4;
    int kk = kb + r, nn = nb + c;
    float v = 0.f;
    if (kk < K && nn < nvalid) v = W[(size_t)kk*ldw + col0 + nn];
    tile[r][c] = v;
  }
  __syncthreads();
  #pragma unroll
  for (int i=0;i<16;i++){
    int r = r4 + i*4;
    T[(size_t)(nb + r)*K + kb + c] = f2bf(tile[c][r]);
  }
}

__global__ __launch_bounds__(256) void k_cvt_dt(const float* __restrict__ xd, bf16* __restrict__ dt){
  int idx = blockIdx.x*256 + threadIdx.x;          // [16384,64] out from xd[:, :64]
  int t = idx >> 6, j = idx & 63;
  dt[idx] = f2bf(xd[(size_t)t*128 + j]);
}

// ---- patch embedding: LN(16) -> Linear(16,1024) -> LN(1024) -> +posemb -> bf16 ----
__global__ __launch_bounds__(256) void k_patch(
    const float* __restrict__ x, const float* __restrict__ g1, const float* __restrict__ b1,
    const float* __restrict__ Wp, const float* __restrict__ bp,
    const float* __restrict__ g2, const float* __restrict__ b2,
    const float* __restrict__ pe, bf16* __restrict__ h)
{
  __shared__ float sp[16];
  __shared__ float red[8];
  int tok = blockIdx.x, tid = threadIdx.x;
  int b = tok >> 9, n = tok & 511;
  if (tid < 16) sp[tid] = x[(size_t)b*CTX + n*16 + tid];
  __syncthreads();
  float m = 0.f;
  #pragma unroll
  for (int i=0;i<16;i++) m += sp[i];
  m *= (1.0f/16.0f);
  float v = 0.f;
  #pragma unroll
  for (int i=0;i<16;i++){ float d = sp[i]-m; v += d*d; }
  v *= (1.0f/16.0f);
  float rs = rsqrtf(v + 1e-5f);
  float pn[16];
  #pragma unroll
  for (int i=0;i<16;i++) pn[i] = (sp[i]-m)*rs*g1[i] + b1[i];
  float acc[4];
  #pragma unroll
  for (int q=0;q<4;q++){
    int j = tid + q*256;
    float a = bp[j];
    #pragma unroll
    for (int i=0;i<16;i++) a += pn[i]*Wp[i*1024 + j];
    acc[q] = a;
  }
  float s1 = acc[0]+acc[1]+acc[2]+acc[3];
  float s2 = acc[0]*acc[0]+acc[1]*acc[1]+acc[2]*acc[2]+acc[3]*acc[3];
  #pragma unroll
  for (int o=32;o;o>>=1){ s1 += __shfl_down(s1,o,64); s2 += __shfl_down(s2,o,64); }
  int w = tid>>6, l = tid&63;
  if (l==0){ red[w]=s1; red[4+w]=s2; }
  __syncthreads();
  float mu  = (red[0]+red[1]+red[2]+red[3])*(1.0f/1024.0f);
  float var = (red[4]+red[5]+red[6]+red[7])*(1.0f/1024.0f) - mu*mu;
  float rs2 = rsqrtf(var + 1e-5f);
  #pragma unroll
  for (int q=0;q<4;q++){
    int j = tid + q*256;
    float val = (acc[q]-mu)*rs2*g2[j] + b2[j] + pe[n*1024 + j];
    h[(size_t)tok*1024 + j] = f2bf(val);
  }
}

// ---- bf16 MFMA GEMM: C[M,N] = A[M,K] @ B[K,N], B given transposed (BT[N,K] row-major) ----
// 128x128 tile, BK=32, 4 waves (2x2), per-wave 64x64 = 4x4 16x16x32 MFMA frags.
// EPI: 0 = plain store, 1 = softplus(acc + bias[col]), 2 = silu(acc).
template<int EPI, typename OT>
__global__ __launch_bounds__(256) void k_gemm_bt(
    const bf16* __restrict__ A, const bf16* __restrict__ BT, OT* __restrict__ C,
    int M, int N, int K, const float* __restrict__ bias)
{
  __shared__ __align__(16) bf16 As[128*32];
  __shared__ __align__(16) bf16 Bs[128*32];
  int tid = threadIdx.x;
  int mblk = M >> 7;
  int bm = blockIdx.x % mblk, bn = blockIdx.x / mblk;
  int m0 = bm << 7, n0 = bn << 7;
  int w = tid >> 6, l = tid & 63, lr = l & 15, lg = l >> 4;
  int wm = w >> 1, wn = w & 1;
  f32x4 acc[4][4] = {};
  int r0 = tid >> 2, c0 = (tid & 3) << 3;
  const bf16* Asrc = A  + (size_t)(m0 + r0) * K + c0;
  const bf16* Bsrc = BT + (size_t)(n0 + r0) * K + c0;
  bf16* AsW = As + w*512;   // wave-uniform LDS base (lane-linear, 64 lanes x 16B)
  bf16* BsW = Bs + w*512;
  for (int kt = 0; kt < K; kt += 32){
    __syncthreads();
    gload_lds16(Asrc + kt,                   AsW);
    gload_lds16(Asrc + (size_t)64*K + kt,    AsW + 2048);
    gload_lds16(Bsrc + kt,                   BsW);
    gload_lds16(Bsrc + (size_t)64*K + kt,    BsW + 2048);
    __syncthreads();
    bf16x8 af[4], bfr[4];
    #pragma unroll
    for (int i=0;i<4;i++) af[i]  = *(const bf16x8*)(As + (wm*64 + i*16 + lr)*32 + lg*8);
    #pragma unroll
    for (int j=0;j<4;j++) bfr[j] = *(const bf16x8*)(Bs + (wn*64 + j*16 + lr)*32 + lg*8);
    #pragma unroll
    for (int i=0;i<4;i++)
      #pragma unroll
      for (int j=0;j<4;j++)
        acc[i][j] = __builtin_amdgcn_mfma_f32_16x16x32_bf16(af[i], bfr[j], acc[i][j], 0,0,0);
  }
  #pragma unroll
  for (int i=0;i<4;i++)
    #pragma unroll
    for (int j=0;j<4;j++)
      #pragma unroll
      for (int r=0;r<4;r++){
        int row = wm*64 + i*16 + lg*4 + r;   // C/D: col=lane&15, row=(lane>>4)*4+reg
        int col = wn*64 + j*16 + lr;
        float v = acc[i][j][r];
        if (EPI == 1) v = softplusf(v + bias[n0 + col]);
        if (EPI == 2) v = v * fast_sigmoid(v);
        stout(&C[(size_t)(m0+row)*N + n0 + col], v);
      }
}

// ---- causal depthwise conv (DC=4) + SiLU, bf16 in/out ; u stride 2048 ----
__global__ __launch_bounds__(256) void k_conv(
    const bf16* __restrict__ u, const float* __restrict__ cw, const float* __restrict__ cb,
    bf16* __restrict__ uc)
{
  const int total = NTOK*DI_;
  for (int idx = blockIdx.x*256 + threadIdx.x; idx < total; idx += gridDim.x*256){
    int d = idx & 2047;
    int tok = idx >> 11;
    int n = tok & 511;
    float a = cb[d];
    #pragma unroll
    for (int k=0;k<4;k++){
      int nn = n + k - 3;
      if (nn >= 0) a += bf2f(u[(size_t)(tok + k - 3)*2048 + d]) * cw[d*4 + k];
    }
    uc[idx] = f2bf(a * fast_sigmoid(a));
  }
}

// ---- selective scan, fused D-skip + gate + token-sum ----
// 4 lanes per d (4 SSM states each); gate g = silu(z) precomputed.
// ysum[b,d] = sum_t (y_t + u_t*D) * g_t
__global__ __launch_bounds__(256) void k_scan(
    const bf16* __restrict__ delta, const bf16* __restrict__ uc, const bf16* __restrict__ g,
    const float* __restrict__ xd, const float* __restrict__ A_log,
    const float* __restrict__ Dp, float* __restrict__ ysum)
{
  int tid = threadIdx.x;
  int q  = tid & 3;          // state quad
  int dl = tid >> 2;         // 64 d per block
  int b  = blockIdx.x >> 5;
  int d  = ((blockIdx.x & 31) << 6) + dl;
  float4 t4 = *(const float4*)(A_log + (size_t)d*16 + q*4);
  float An0 = -__expf(t4.x), An1 = -__expf(t4.y), An2 = -__expf(t4.z), An3 = -__expf(t4.w);
  float Dd = (q == 0) ? Dp[d] : 0.0f;
  float h0=0.f,h1=0.f,h2=0.f,h3=0.f;
  float acc = 0.0f;
  size_t tok0 = (size_t)b * 512;
  for (int t=0; t<512; ++t){
    size_t tok = tok0 + t;
    float dt = bf2f(delta[tok*2048 + d]);
    float ut = bf2f(uc[tok*2048 + d]);
    float gt = bf2f(g[tok*2048 + d]);
    const float4* x4 = (const float4*)(xd + tok*128);   // cols: 0..63 dt, 64..79 B, 80..95 C
    float4 Bq = x4[16+q];
    float4 Cq = x4[20+q];
    float du = dt*ut;
    float y = 0.0f;
    float e;
    e = __expf(dt*An0); h0 = h0*e + du*Bq.x; y += h0*Cq.x;
    e = __expf(dt*An1); h1 = h1*e + du*Bq.y; y += h1*Cq.y;
    e = __expf(dt*An2); h2 = h2*e + du*Bq.z; y += h2*Cq.z;
    e = __expf(dt*An3); h3 = h3*e + du*Bq.w; y += h3*Cq.w;
    acc += (y + ut*Dd) * gt;
  }
  acc += __shfl_xor(acc, 1, 64);
  acc += __shfl_xor(acc, 2, 64);
  if (q == 0) ysum[(size_t)b*2048 + d] = acc;
}

// ---- pooled = (ysum/NP) @ W_out : [32,2048] @ [2048,1024] ----
__global__ __launch_bounds__(256) void k_poolgemm(
    const float* __restrict__ ysum, const float* __restrict__ Wo, float* __restrict__ pooled)
{
  __shared__ float ys[32*128];
  int tid = threadIdx.x;
  int nb = blockIdx.x;                  // 16 blocks x 64 cols
  int jj = tid & 63, b0 = tid >> 6;
  int j = nb*64 + jj;
  float acc[8];
  #pragma unroll
  for (int p=0;p<8;p++) acc[p] = 0.f;
  for (int kc=0; kc<2048; kc+=128){
    __syncthreads();
    #pragma unroll
    for (int i=0;i<16;i++){
      int e = tid + i*256;
      int bb = e >> 7, kk = e & 127;
      ys[bb*128 + kk] = ysum[(size_t)bb*2048 + kc + kk];
    }
    __syncthreads();
    for (int kk=0;kk<128;kk++){
      float wv = Wo[(size_t)(kc+kk)*1024 + j];
      #pragma unroll
      for (int p=0;p<8;p++) acc[p] += ys[(b0 + p*4)*128 + kk] * wv;
    }
  }
  #pragma unroll
  for (int p=0;p<8;p++) pooled[(size_t)(b0 + p*4)*1024 + j] = acc[p] * (1.0f/512.0f);
}

// ---- head: LN(1024) -> dot Wh + bh ----
__global__ __launch_bounds__(256) void k_head(
    const float* __restrict__ pooled, const float* __restrict__ g, const float* __restrict__ bb,
    const float* __restrict__ Wh, const float* __restrict__ bh, float* __restrict__ out)
{
  __shared__ float red[8];
  int b = blockIdx.x, tid = threadIdx.x;
  float v[4];
  #pragma unroll
  for (int q=0;q<4;q++) v[q] = pooled[(size_t)b*1024 + tid + q*256];
  float s1 = v[0]+v[1]+v[2]+v[3];
  float s2 = v[0]*v[0]+v[1]*v[1]+v[2]*v[2]+v[3]*v[3];
  #pragma unroll
  for (int o=32;o;o>>=1){ s1 += __shfl_down(s1,o,64); s2 += __shfl_down(s2,o,64); }
  int w = tid>>6, l = tid&63;
  if (l==0){ red[w]=s1; red[4+w]=s2; }
  __syncthreads();
  float mu  = (red[0]+red[1]+red[2]+red[3])*(1.0f/1024.0f);
  float var = (red[4]+red[5]+red[6]+red[7])*(1.0f/1024.0f) - mu*mu;
  float rs = rsqrtf(var + 1e-5f);
  float p = 0.f;
  #pragma unroll
  for (int q=0;q<4;q++){
    int jv = tid + q*256;
    p += ((v[q]-mu)*rs*g[jv] + bb[jv]) * Wh[jv];
  }
  #pragma unroll
  for (int o=32;o;o>>=1) p += __shfl_down(p,o,64);
  __syncthreads();
  if (l==0) red[w] = p;
  __syncthreads();
  if (tid==0) out[b] = red[0]+red[1]+red[2]+red[3] + bh[0];
}

extern "C" void kernel_launch(void* const* d_in, const int* in_sizes, int n_in,
                              void* d_out, int out_size, void* d_ws, size_t ws_size,
                              hipStream_t stream)
{
  const float* x     = (const float*)d_in[0];
  const float* ln1_g = (const float*)d_in[1];
  const float* ln1_b = (const float*)d_in[2];
  const float* Wp    = (const float*)d_in[3];
  const float* bp    = (const float*)d_in[4];
  const float* ln2_g = (const float*)d_in[5];
  const float* ln2_b = (const float*)d_in[6];
  const float* W_in  = (const float*)d_in[7];
  const float* conv_w= (const float*)d_in[8];
  const float* conv_b= (const float*)d_in[9];
  const float* W_x   = (const float*)d_in[10];
  const float* W_dt  = (const float*)d_in[11];
  const float* b_dt  = (const float*)d_in[12];
  const float* A_log = (const float*)d_in[13];
  const float* Dv    = (const float*)d_in[14];
  const float* W_out = (const float*)d_in[15];
  const float* ln3_g = (const float*)d_in[16];
  const float* ln3_b = (const float*)d_in[17];
  const float* Wh    = (const float*)d_in[18];
  const float* bh    = (const float*)d_in[19];

  // ---- workspace layout with liveness-based aliasing; peak = 230 MiB ----
  char* ws = (char*)d_ws;
  size_t o = 0;
  bf16*  u_delta = (bf16*)(ws + o); o += (size_t)NTOK*DI_*2;   // 64 MiB: u, later delta
  bf16*  zbuf    = (bf16*)(ws + o); o += (size_t)NTOK*DI_*2;   // 64 MiB: g = silu(z)
  bf16*  ucbuf   = (bf16*)(ws + o); o += (size_t)NTOK*DI_*2;   // 64 MiB: uc (persistent)
  char*  poolA   = (ws + o);        o += (size_t)NTOK*DM_*2;   // 32 MiB: h, later xd/dt/...
  bf16*  winTh   = (bf16*)(ws + o); o += (size_t)DI_*DM_*2;    //  4 MiB: one in_proj half ^T
  float* pe      = (float*)(ws + o); o += (size_t)NP_*DM_*4;   //  2 MiB
  // poolA phase-1: h [16384,1024] bf16
  bf16*  hbuf    = (bf16*)poolA;
  // poolA phase-2 (after in_proj GEMMs): xd, dt, wxT, wdtT, ysum, pooled
  float* xdbuf   = (float*)(poolA + 0);          // 8.0 MiB  [16384,128] f32
  bf16*  dtbuf   = (bf16*) (poolA + 8388608);    // 2.0 MiB  [16384,64]
  bf16*  wxT     = (bf16*) (poolA + 10485760);   // 0.5 MiB  [128,2048]
  bf16*  wdtT    = (bf16*) (poolA + 11010048);   // 0.25 MiB [2048,64]
  float* ysumbuf = (float*)(poolA + 11272192);   // 0.25 MiB [32,2048]
  float* pooledb = (float*)(poolA + 11534336);   // 0.13 MiB [32,1024]

  k_posemb        <<<2048, 256, 0, stream>>>(pe);
  k_patch         <<<16384,256, 0, stream>>>(x, ln1_g, ln1_b, Wp, bp, ln2_g, ln2_b, pe, hbuf);
  // in_proj, u half then z half (winTh reused); z-half epilogue = silu
  k_transpose_cvt <<<dim3(16,32),256,0,stream>>>(W_in, winTh, 4096, 0,    2048, 1024);
  k_gemm_bt<0,bf16><<<2048,256, 0, stream>>>(hbuf, winTh, u_delta, NTOK, 2048, 1024, nullptr);
  k_transpose_cvt <<<dim3(16,32),256,0,stream>>>(W_in, winTh, 4096, 2048, 2048, 1024);
  k_gemm_bt<2,bf16><<<2048,256, 0, stream>>>(hbuf, winTh, zbuf,    NTOK, 2048, 1024, nullptr);
  // conv(u) -> uc   (hbuf dead from here; poolA reused)
  k_conv          <<<8192, 256, 0, stream>>>(u_delta, conv_w, conv_b, ucbuf);
  // x_proj: xd = uc @ W_x  (N padded 96->128)
  k_transpose_cvt <<<dim3(32,2),256,0,stream>>>(W_x, wxT, 96, 0, 96, 2048);
  k_gemm_bt<0,float><<<128,256, 0, stream>>>(ucbuf, wxT, xdbuf, NTOK, 128, 2048, nullptr);
  // delta = softplus(dt @ W_dt + b_dt)  (overwrites u, dead after conv)
  k_cvt_dt        <<<4096, 256, 0, stream>>>(xdbuf, dtbuf);
  k_transpose_cvt <<<dim3(1,32),256,0,stream>>>(W_dt, wdtT, 2048, 0, 2048, 64);
  k_gemm_bt<1,bf16><<<2048,256, 0, stream>>>(dtbuf, wdtT, u_delta, NTOK, 2048, 64, b_dt);
  // fused scan + D-skip + gate + token-sum (4 lanes per d)
  k_scan          <<<1024, 256, 0, stream>>>(u_delta, ucbuf, zbuf, xdbuf, A_log, Dv, ysumbuf);
  // pooled = (ysum/512) @ W_out ; head
  k_poolgemm      <<<16,   256, 0, stream>>>(ysumbuf, W_out, pooledb);
  k_head          <<<32,   256, 0, stream>>>(pooledb, ln3_g, ln3_b, Wh, bh, (float*)d_out);
  (void)in_sizes; (void)n_in; (void)out_size; (void)ws_size;
}

// Round 4
// 768.265 us; speedup vs baseline: 1.3811x; 1.2298x over previous
//
#include <hip/hip_runtime.h>
#include <hip/hip_bf16.h>

// ---- problem constants ----
#define BSZ  32
#define CTX  8192
#define NP_  512
#define PSZ  16
#define DM_  1024
#define DS_  16
#define DI_  2048
#define DTR_ 64
#define NTOK (BSZ*NP_)   // 16384

typedef __hip_bfloat16 bf16;
typedef short bf16x8 __attribute__((ext_vector_type(8)));
typedef float f32x4  __attribute__((ext_vector_type(4)));

typedef __attribute__((address_space(3))) void lds_t;
typedef __attribute__((address_space(1))) void gbl_t;

__device__ inline float bf2f(bf16 v){ return __bfloat162float(v); }
__device__ inline bf16  f2bf(float v){ return __float2bfloat16(v); }
__device__ inline float fast_sigmoid(float x){ return 1.0f/(1.0f+__expf(-x)); }
__device__ inline float softplusf(float x){ return x>15.0f ? x : log1pf(__expf(x)); }
__device__ inline void stout(float* p, float v){ *p = v; }
__device__ inline void stout(bf16* p, float v){ *p = f2bf(v); }

__device__ inline void gload_lds16(const void* g, void* l){
  __builtin_amdgcn_global_load_lds((const gbl_t*)g, (lds_t*)l, 16, 0, 0);
}

// ---- sincos positional embedding table [NP, DM] ----
__global__ __launch_bounds__(256) void k_posemb(float* __restrict__ pe){
  int idx = blockIdx.x*256 + threadIdx.x;          // 512*1024
  int n = idx >> 10, c = idx & 1023;
  int j2 = c & 511;
  float omega = exp2f(-13.2877123795495f * ((float)j2 * (1.0f/511.0f)));
  float ang = (float)n * omega;
  pe[idx] = (c < 512) ? sinf(ang) : cosf(ang);
}

// ---- coalesced transpose + f32->bf16: T[n][k] = W[k][col0+n] (n<nvalid else 0) ----
// T is [Nout, K] row-major, grid = (K/64, Nout/64), 64x64 LDS tile.
__global__ __launch_bounds__(256) void k_transpose_cvt(
    const float* __restrict__ W, bf16* __restrict__ T,
    int ldw, int col0, int nvalid, int K)
{
  __shared__ float tile[64][65];
  int tid = threadIdx.x;
  int kb = blockIdx.x << 6, nb = blockIdx.y << 6;
  int c = tid & 63, r4 = tid >> 6;
  #pragma unroll
  for (int i=0;i<16;i++){
    int r = r4 + i*4;
    int kk = kb + r, nn = nb + c;
    float v = 0.f;
    if (kk < K && nn < nvalid) v = W[(size_t)kk*ldw + col0 + nn];
    tile[r][c] = v;
  }
  __syncthreads();
  #pragma unroll
  for (int i=0;i<16;i++){
    int r = r4 + i*4;
    T[(size_t)(nb + r)*K + kb + c] = f2bf(tile[c][r]);
  }
}

__global__ __launch_bounds__(256) void k_cvt_dt(const float* __restrict__ xd, bf16* __restrict__ dt){
  int idx = blockIdx.x*256 + threadIdx.x;          // [16384,64] out from xd[:, :64]
  int t = idx >> 6, j = idx & 63;
  dt[idx] = f2bf(xd[(size_t)t*128 + j]);
}

// ---- patch embedding: LN(16) -> Linear(16,1024) -> LN(1024) -> +posemb -> bf16 ----
__global__ __launch_bounds__(256) void k_patch(
    const float* __restrict__ x, const float* __restrict__ g1, const float* __restrict__ b1,
    const float* __restrict__ Wp, const float* __restrict__ bp,
    const float* __restrict__ g2, const float* __restrict__ b2,
    const float* __restrict__ pe, bf16* __restrict__ h)
{
  __shared__ float sp[16];
  __shared__ float red[8];
  int tok = blockIdx.x, tid = threadIdx.x;
  int b = tok >> 9, n = tok & 511;
  if (tid < 16) sp[tid] = x[(size_t)b*CTX + n*16 + tid];
  __syncthreads();
  float m = 0.f;
  #pragma unroll
  for (int i=0;i<16;i++) m += sp[i];
  m *= (1.0f/16.0f);
  float v = 0.f;
  #pragma unroll
  for (int i=0;i<16;i++){ float d = sp[i]-m; v += d*d; }
  v *= (1.0f/16.0f);
  float rs = rsqrtf(v + 1e-5f);
  float pn[16];
  #pragma unroll
  for (int i=0;i<16;i++) pn[i] = (sp[i]-m)*rs*g1[i] + b1[i];
  float acc[4];
  #pragma unroll
  for (int q=0;q<4;q++){
    int j = tid + q*256;
    float a = bp[j];
    #pragma unroll
    for (int i=0;i<16;i++) a += pn[i]*Wp[i*1024 + j];
    acc[q] = a;
  }
  float s1 = acc[0]+acc[1]+acc[2]+acc[3];
  float s2 = acc[0]*acc[0]+acc[1]*acc[1]+acc[2]*acc[2]+acc[3]*acc[3];
  #pragma unroll
  for (int o=32;o;o>>=1){ s1 += __shfl_down(s1,o,64); s2 += __shfl_down(s2,o,64); }
  int w = tid>>6, l = tid&63;
  if (l==0){ red[w]=s1; red[4+w]=s2; }
  __syncthreads();
  float mu  = (red[0]+red[1]+red[2]+red[3])*(1.0f/1024.0f);
  float var = (red[4]+red[5]+red[6]+red[7])*(1.0f/1024.0f) - mu*mu;
  float rs2 = rsqrtf(var + 1e-5f);
  #pragma unroll
  for (int q=0;q<4;q++){
    int j = tid + q*256;
    float val = (acc[q]-mu)*rs2*g2[j] + b2[j] + pe[n*1024 + j];
    h[(size_t)tok*1024 + j] = f2bf(val);
  }
}

// ---- bf16 MFMA GEMM: C[M,N] = A[M,K] @ B[K,N], B given transposed (BT[N,K] row-major) ----
// 128x128 tile, BK=32, 4 waves (2x2), per-wave 64x64 = 4x4 16x16x32 MFMA frags.
// EPI: 0 = plain store, 1 = softplus(acc + bias[col]), 2 = silu(acc).
template<int EPI, typename OT>
__global__ __launch_bounds__(256) void k_gemm_bt(
    const bf16* __restrict__ A, const bf16* __restrict__ BT, OT* __restrict__ C,
    int M, int N, int K, const float* __restrict__ bias)
{
  __shared__ __align__(16) bf16 As[128*32];
  __shared__ __align__(16) bf16 Bs[128*32];
  int tid = threadIdx.x;
  int mblk = M >> 7;
  int bm = blockIdx.x % mblk, bn = blockIdx.x / mblk;
  int m0 = bm << 7, n0 = bn << 7;
  int w = tid >> 6, l = tid & 63, lr = l & 15, lg = l >> 4;
  int wm = w >> 1, wn = w & 1;
  f32x4 acc[4][4] = {};
  int r0 = tid >> 2, c0 = (tid & 3) << 3;
  const bf16* Asrc = A  + (size_t)(m0 + r0) * K + c0;
  const bf16* Bsrc = BT + (size_t)(n0 + r0) * K + c0;
  bf16* AsW = As + w*512;   // wave-uniform LDS base (lane-linear, 64 lanes x 16B)
  bf16* BsW = Bs + w*512;
  for (int kt = 0; kt < K; kt += 32){
    __syncthreads();
    gload_lds16(Asrc + kt,                   AsW);
    gload_lds16(Asrc + (size_t)64*K + kt,    AsW + 2048);
    gload_lds16(Bsrc + kt,                   BsW);
    gload_lds16(Bsrc + (size_t)64*K + kt,    BsW + 2048);
    __syncthreads();
    bf16x8 af[4], bfr[4];
    #pragma unroll
    for (int i=0;i<4;i++) af[i]  = *(const bf16x8*)(As + (wm*64 + i*16 + lr)*32 + lg*8);
    #pragma unroll
    for (int j=0;j<4;j++) bfr[j] = *(const bf16x8*)(Bs + (wn*64 + j*16 + lr)*32 + lg*8);
    #pragma unroll
    for (int i=0;i<4;i++)
      #pragma unroll
      for (int j=0;j<4;j++)
        acc[i][j] = __builtin_amdgcn_mfma_f32_16x16x32_bf16(af[i], bfr[j], acc[i][j], 0,0,0);
  }
  #pragma unroll
  for (int i=0;i<4;i++)
    #pragma unroll
    for (int j=0;j<4;j++)
      #pragma unroll
      for (int r=0;r<4;r++){
        int row = wm*64 + i*16 + lg*4 + r;   // C/D: col=lane&15, row=(lane>>4)*4+reg
        int col = wn*64 + j*16 + lr;
        float v = acc[i][j][r];
        if (EPI == 1) v = softplusf(v + bias[n0 + col]);
        if (EPI == 2) v = v * fast_sigmoid(v);
        stout(&C[(size_t)(m0+row)*N + n0 + col], v);
      }
}

// ---- causal depthwise conv (DC=4) + SiLU, bf16 in/out ; u stride 2048 ----
__global__ __launch_bounds__(256) void k_conv(
    const bf16* __restrict__ u, const float* __restrict__ cw, const float* __restrict__ cb,
    bf16* __restrict__ uc)
{
  const int total = NTOK*DI_;
  for (int idx = blockIdx.x*256 + threadIdx.x; idx < total; idx += gridDim.x*256){
    int d = idx & 2047;
    int tok = idx >> 11;
    int n = tok & 511;
    float a = cb[d];
    #pragma unroll
    for (int k=0;k<4;k++){
      int nn = n + k - 3;
      if (nn >= 0) a += bf2f(u[(size_t)(tok + k - 3)*2048 + d]) * cw[d*4 + k];
    }
    uc[idx] = f2bf(a * fast_sigmoid(a));
  }
}

// ---- selective scan, fused D-skip + gate + token-sum ----
// 4 lanes per d (4 SSM states each); gate g = silu(z) precomputed.
// ysum[b,d] = sum_t (y_t + u_t*D) * g_t
__global__ __launch_bounds__(256) void k_scan(
    const bf16* __restrict__ delta, const bf16* __restrict__ uc, const bf16* __restrict__ g,
    const float* __restrict__ xd, const float* __restrict__ A_log,
    const float* __restrict__ Dp, float* __restrict__ ysum)
{
  int tid = threadIdx.x;
  int q  = tid & 3;          // state quad
  int dl = tid >> 2;         // 64 d per block
  int b  = blockIdx.x >> 5;
  int d  = ((blockIdx.x & 31) << 6) + dl;
  float4 t4 = *(const float4*)(A_log + (size_t)d*16 + q*4);
  float An0 = -__expf(t4.x), An1 = -__expf(t4.y), An2 = -__expf(t4.z), An3 = -__expf(t4.w);
  float Dd = (q == 0) ? Dp[d] : 0.0f;
  float h0=0.f,h1=0.f,h2=0.f,h3=0.f;
  float acc = 0.0f;
  size_t tok0 = (size_t)b * 512;
  for (int t=0; t<512; ++t){
    size_t tok = tok0 + t;
    float dt = bf2f(delta[tok*2048 + d]);
    float ut = bf2f(uc[tok*2048 + d]);
    float gt = bf2f(g[tok*2048 + d]);
    const float4* x4 = (const float4*)(xd + tok*128);   // cols: 0..63 dt, 64..79 B, 80..95 C
    float4 Bq = x4[16+q];
    float4 Cq = x4[20+q];
    float du = dt*ut;
    float y = 0.0f;
    float e;
    e = __expf(dt*An0); h0 = h0*e + du*Bq.x; y += h0*Cq.x;
    e = __expf(dt*An1); h1 = h1*e + du*Bq.y; y += h1*Cq.y;
    e = __expf(dt*An2); h2 = h2*e + du*Bq.z; y += h2*Cq.z;
    e = __expf(dt*An3); h3 = h3*e + du*Bq.w; y += h3*Cq.w;
    acc += (y + ut*Dd) * gt;
  }
  acc += __shfl_xor(acc, 1, 64);
  acc += __shfl_xor(acc, 2, 64);
  if (q == 0) ysum[(size_t)b*2048 + d] = acc;
}

// ---- split-K pooled GEMM part 1: partial[kc][b][j] = sum_{k in chunk kc} ys[b][k]*Wo[k][j] ----
// grid = 16 j-blocks x 32 k-chunks (64 k each); per-wave b-group is wave-uniform
// so LDS ys reads are same-address broadcasts (conflict-free).
__global__ __launch_bounds__(256) void k_poolgemm_part(
    const float* __restrict__ ysum, const float* __restrict__ Wo, float* __restrict__ partial)
{
  __shared__ float ys[32][64];
  int tid = threadIdx.x;
  int jb = blockIdx.x & 15;
  int kc = blockIdx.x >> 4;
  int j  = jb*64 + (tid & 63);
  int b0 = tid >> 6;             // wave id: 8 b's per wave
  #pragma unroll
  for (int i=0;i<8;i++){
    int e = tid + i*256;
    int bb = e >> 6, kk = e & 63;
    ys[bb][kk] = ysum[(size_t)bb*2048 + kc*64 + kk];
  }
  __syncthreads();
  float acc[8];
  #pragma unroll
  for (int p=0;p<8;p++) acc[p] = 0.f;
  #pragma unroll 4
  for (int kk=0;kk<64;kk++){
    float wv = Wo[(size_t)(kc*64 + kk)*1024 + j];
    #pragma unroll
    for (int p=0;p<8;p++) acc[p] += ys[b0*8 + p][kk] * wv;
  }
  #pragma unroll
  for (int p=0;p<8;p++)
    partial[((size_t)kc*32 + b0*8 + p)*1024 + j] = acc[p];
}

// ---- split-K pooled GEMM part 2: pooled[b][j] = (1/512) * sum_kc partial[kc][b][j] ----
__global__ __launch_bounds__(256) void k_pool_reduce(
    const float* __restrict__ partial, float* __restrict__ pooled)
{
  int idx = blockIdx.x*256 + threadIdx.x;    // 32*1024 = 32768
  float s = 0.f;
  #pragma unroll 8
  for (int kc=0;kc<32;kc++) s += partial[(size_t)kc*32768 + idx];
  pooled[idx] = s * (1.0f/512.0f);
}

// ---- head: LN(1024) -> dot Wh + bh ----
__global__ __launch_bounds__(256) void k_head(
    const float* __restrict__ pooled, const float* __restrict__ g, const float* __restrict__ bb,
    const float* __restrict__ Wh, const float* __restrict__ bh, float* __restrict__ out)
{
  __shared__ float red[8];
  int b = blockIdx.x, tid = threadIdx.x;
  float v[4];
  #pragma unroll
  for (int q=0;q<4;q++) v[q] = pooled[(size_t)b*1024 + tid + q*256];
  float s1 = v[0]+v[1]+v[2]+v[3];
  float s2 = v[0]*v[0]+v[1]*v[1]+v[2]*v[2]+v[3]*v[3];
  #pragma unroll
  for (int o=32;o;o>>=1){ s1 += __shfl_down(s1,o,64); s2 += __shfl_down(s2,o,64); }
  int w = tid>>6, l = tid&63;
  if (l==0){ red[w]=s1; red[4+w]=s2; }
  __syncthreads();
  float mu  = (red[0]+red[1]+red[2]+red[3])*(1.0f/1024.0f);
  float var = (red[4]+red[5]+red[6]+red[7])*(1.0f/1024.0f) - mu*mu;
  float rs = rsqrtf(var + 1e-5f);
  float p = 0.f;
  #pragma unroll
  for (int q=0;q<4;q++){
    int jv = tid + q*256;
    p += ((v[q]-mu)*rs*g[jv] + bb[jv]) * Wh[jv];
  }
  #pragma unroll
  for (int o=32;o;o>>=1) p += __shfl_down(p,o,64);
  __syncthreads();
  if (l==0) red[w] = p;
  __syncthreads();
  if (tid==0) out[b] = red[0]+red[1]+red[2]+red[3] + bh[0];
}

extern "C" void kernel_launch(void* const* d_in, const int* in_sizes, int n_in,
                              void* d_out, int out_size, void* d_ws, size_t ws_size,
                              hipStream_t stream)
{
  const float* x     = (const float*)d_in[0];
  const float* ln1_g = (const float*)d_in[1];
  const float* ln1_b = (const float*)d_in[2];
  const float* Wp    = (const float*)d_in[3];
  const float* bp    = (const float*)d_in[4];
  const float* ln2_g = (const float*)d_in[5];
  const float* ln2_b = (const float*)d_in[6];
  const float* W_in  = (const float*)d_in[7];
  const float* conv_w= (const float*)d_in[8];
  const float* conv_b= (const float*)d_in[9];
  const float* W_x   = (const float*)d_in[10];
  const float* W_dt  = (const float*)d_in[11];
  const float* b_dt  = (const float*)d_in[12];
  const float* A_log = (const float*)d_in[13];
  const float* Dv    = (const float*)d_in[14];
  const float* W_out = (const float*)d_in[15];
  const float* ln3_g = (const float*)d_in[16];
  const float* ln3_b = (const float*)d_in[17];
  const float* Wh    = (const float*)d_in[18];
  const float* bh    = (const float*)d_in[19];

  // ---- workspace layout with liveness-based aliasing; peak = 230 MiB ----
  char* ws = (char*)d_ws;
  size_t o = 0;
  bf16*  u_delta = (bf16*)(ws + o); o += (size_t)NTOK*DI_*2;   // 64 MiB: u, later delta
  bf16*  zbuf    = (bf16*)(ws + o); o += (size_t)NTOK*DI_*2;   // 64 MiB: g = silu(z)
  bf16*  ucbuf   = (bf16*)(ws + o); o += (size_t)NTOK*DI_*2;   // 64 MiB: uc (persistent)
  char*  poolA   = (ws + o);        o += (size_t)NTOK*DM_*2;   // 32 MiB: h, later xd/dt/...
  bf16*  winTh   = (bf16*)(ws + o); o += (size_t)DI_*DM_*2;    //  4 MiB: one in_proj half ^T
  float* pe      = (float*)(ws + o); o += (size_t)NP_*DM_*4;   //  2 MiB
  // poolA phase-1: h [16384,1024] bf16
  bf16*  hbuf    = (bf16*)poolA;
  // poolA phase-2 (after in_proj GEMMs): xd, dt, wxT, wdtT, ysum, pooled, partial
  float* xdbuf   = (float*)(poolA + 0);          // 8.0 MiB  [16384,128] f32
  bf16*  dtbuf   = (bf16*) (poolA + 8388608);    // 2.0 MiB  [16384,64]
  bf16*  wxT     = (bf16*) (poolA + 10485760);   // 0.5 MiB  [128,2048]
  bf16*  wdtT    = (bf16*) (poolA + 11010048);   // 0.25 MiB [2048,64]
  float* ysumbuf = (float*)(poolA + 11272192);   // 0.25 MiB [32,2048]
  float* pooledb = (float*)(poolA + 11534336);   // 0.13 MiB [32,1024]
  float* partial = (float*)(poolA + 12582912);   // 4.0 MiB  [32,32,1024]

  k_posemb        <<<2048, 256, 0, stream>>>(pe);
  k_patch         <<<16384,256, 0, stream>>>(x, ln1_g, ln1_b, Wp, bp, ln2_g, ln2_b, pe, hbuf);
  // in_proj, u half then z half (winTh reused); z-half epilogue = silu
  k_transpose_cvt <<<dim3(16,32),256,0,stream>>>(W_in, winTh, 4096, 0,    2048, 1024);
  k_gemm_bt<0,bf16><<<2048,256, 0, stream>>>(hbuf, winTh, u_delta, NTOK, 2048, 1024, nullptr);
  k_transpose_cvt <<<dim3(16,32),256,0,stream>>>(W_in, winTh, 4096, 2048, 2048, 1024);
  k_gemm_bt<2,bf16><<<2048,256, 0, stream>>>(hbuf, winTh, zbuf,    NTOK, 2048, 1024, nullptr);
  // conv(u) -> uc   (hbuf dead from here; poolA reused)
  k_conv          <<<8192, 256, 0, stream>>>(u_delta, conv_w, conv_b, ucbuf);
  // x_proj: xd = uc @ W_x  (N padded 96->128)
  k_transpose_cvt <<<dim3(32,2),256,0,stream>>>(W_x, wxT, 96, 0, 96, 2048);
  k_gemm_bt<0,float><<<128,256, 0, stream>>>(ucbuf, wxT, xdbuf, NTOK, 128, 2048, nullptr);
  // delta = softplus(dt @ W_dt + b_dt)  (overwrites u, dead after conv)
  k_cvt_dt        <<<4096, 256, 0, stream>>>(xdbuf, dtbuf);
  k_transpose_cvt <<<dim3(1,32),256,0,stream>>>(W_dt, wdtT, 2048, 0, 2048, 64);
  k_gemm_bt<1,bf16><<<2048,256, 0, stream>>>(dtbuf, wdtT, u_delta, NTOK, 2048, 64, b_dt);
  // fused scan + D-skip + gate + token-sum (4 lanes per d)
  k_scan          <<<1024, 256, 0, stream>>>(u_delta, ucbuf, zbuf, xdbuf, A_log, Dv, ysumbuf);
  // pooled = (ysum/512) @ W_out : split-K over 512 blocks, then reduce
  k_poolgemm_part <<<512,  256, 0, stream>>>(ysumbuf, W_out, partial);
  k_pool_reduce   <<<128,  256, 0, stream>>>(partial, pooledb);
  k_head          <<<32,   256, 0, stream>>>(pooledb, ln3_g, ln3_b, Wh, bh, (float*)d_out);
  (void)in_sizes; (void)n_in; (void)out_size; (void)ws_size;
}